// Round 7
// baseline (284.600 us; speedup 1.0000x reference)
//
#include <hip/hip_runtime.h>
#include <hip/hip_bf16.h>

typedef __attribute__((ext_vector_type(8))) short short8;
typedef __attribute__((ext_vector_type(4))) float f32x4;

// bf16 helpers (hardware v_cvt_pk_bf16_f32 via HIP intrinsics).
__device__ __forceinline__ float b2f(short s) {
    return __uint_as_float(((unsigned int)(unsigned short)s) << 16);
}
__device__ __forceinline__ float b2f_lo(unsigned u) {      // low bf16 of dword
    return __uint_as_float(u << 16);
}
__device__ __forceinline__ float b2f_hi(unsigned u) {      // high bf16: 1 op
    return __uint_as_float(u & 0xffff0000u);
}
__device__ __forceinline__ short f2b(float f) {
    union { __hip_bfloat16 h; short s; } cv;
    cv.h = __float2bfloat16(f);
    return cv.s;
}
__device__ __forceinline__ unsigned pack2(float a, float b) {
    union { __hip_bfloat162 h; unsigned u; } cv;
    cv.h = __float22bfloat162_rn(make_float2(a, b));
    return cv.u;
}

// ============================================================================
// K0: one-off prep (~2us).
//   ucotT[co][r] = bf16(Uco[r][co])   (4096)  - k2 phase-C B-operand (global)
//   ucinT[r][c]  = bf16(Ucin[c][r])   (2048)  - k1 MFMA A-operand
// ============================================================================
__global__ __launch_bounds__(64)
void k0_prep(const float* __restrict__ Uco, const float* __restrict__ Ucin,
             short* __restrict__ ucotT, short* __restrict__ ucinT)
{
    const int i = blockIdx.x * 64 + threadIdx.x;    // 0..6143
    if (i < 4096) {
        int co = i >> 6, r = i & 63;
        ucotT[co * 64 + r] = f2b(Uco[r * 64 + co]);
    } else {
        int j = i - 4096;                           // 0..2047
        int r = j >> 5, c = j & 31;
        ucinT[r * 32 + c] = f2b(Ucin[c * 64 + r]);
    }
}

// ============================================================================
// K1 (unchanged): channel contraction as MFMA GEMM.
//   t[sp][r] = sum_c x[c][sp] * Ucin[c][r]
// ============================================================================
__global__ __launch_bounds__(256)
void k1_channel(const float* __restrict__ x,
                const float* __restrict__ Ucin,
                const short* __restrict__ ucinT_g,   // may be null
                short* __restrict__ t)
{
    __shared__ short xs[256 * 32];    // 16 KB  x^T tile, swizzled 16B slots
    __shared__ short uci[64 * 32];    //  4 KB  Ucin^T [r][c], linear

    const int tid = threadIdx.x;
    const int gp0 = blockIdx.x * 256;              // 2048 blocks, same b per block
    const int b   = gp0 >> 18;
    const int sp  = (gp0 & 262143) + tid;
    const float* xp = x + ((long)b << 23) + sp;

    if (ucinT_g) {
        ((short8*)uci)[tid] = ((const short8*)ucinT_g)[tid];
    } else {
        for (int i = tid; i < 2048; i += 256) {
            int r = i >> 5, c = i & 31;
            uci[i] = f2b(Ucin[c * 64 + r]);
        }
    }

    // stage x^T tile: thread owns sp-row tid; 32 coalesced load streams
    {
        float v[32];
#pragma unroll
        for (int c = 0; c < 32; ++c) v[c] = xp[(long)c << 18];
        const int swz = (tid >> 1) & 3;
#pragma unroll
        for (int oct = 0; oct < 4; ++oct) {
            uint4 o;
            o.x = pack2(v[oct * 8 + 0], v[oct * 8 + 1]);
            o.y = pack2(v[oct * 8 + 2], v[oct * 8 + 3]);
            o.z = pack2(v[oct * 8 + 4], v[oct * 8 + 5]);
            o.w = pack2(v[oct * 8 + 6], v[oct * 8 + 7]);
            *(uint4*)&xs[tid * 32 + ((oct ^ swz) << 3)] = o;
        }
    }
    __syncthreads();

    const int lane = tid & 63, wv = tid >> 6;
    const int l15 = lane & 15, quad = lane >> 4;

    short8 afr[4];
#pragma unroll
    for (int mt = 0; mt < 4; ++mt)
        afr[mt] = *(const short8*)&uci[(mt * 16 + l15) * 32 + quad * 8];

    f32x4 acc[4][4] = {};
#pragma unroll
    for (int nt = 0; nt < 4; ++nt) {
        const int srow = wv * 64 + nt * 16 + l15;
        const int slot = quad ^ ((srow >> 1) & 3);
        short8 bfr = *(const short8*)&xs[srow * 32 + (slot << 3)];
#pragma unroll
        for (int mt = 0; mt < 4; ++mt)
            acc[mt][nt] = __builtin_amdgcn_mfma_f32_16x16x32_bf16(
                afr[mt], bfr, acc[mt][nt], 0, 0, 0);
    }

#pragma unroll
    for (int nt = 0; nt < 4; ++nt) {
        const int srow = wv * 64 + nt * 16 + l15;
        short* tb = t + ((size_t)(gp0 + srow) << 6);
#pragma unroll
        for (int mt = 0; mt < 4; ++mt) {
            uint2 o;
            o.x = pack2(acc[mt][nt][0], acc[mt][nt][1]);
            o.y = pack2(acc[mt][nt][2], acc[mt][nt][3]);
            *(uint2*)&tb[mt * 16 + quad * 4] = o;
        }
    }
}

// ============================================================================
// K2 (round-7): drop the ucot LDS buffer + staging entirely.
//   Phase C reads its 8 B-fragments (Uco^T) straight from global ucotT
//   (coalesced 16B/lane, 32KB grid-wide -> L2-hit; round-5 gk run proved
//   per-wave global B-frag loads are cheap — its loss was the 3x K, not these).
//   LDS 27136 -> 17664 B: block cap 5 -> 8 per CU (32 waves = HW max).
//   phase A: hw-conv, software-pipelined 4 items/thread from 9 neighbor cols
//   phase B: d-conv -> p[64][72]
//   phase C: out GEMM M=64(d) N=64(co) K=64(r) + bias
// ============================================================================
__global__ __launch_bounds__(256)
void k2_conv_gemm(const short* __restrict__ t,
                  const float* __restrict__ Ukh,
                  const float* __restrict__ Ukw,
                  const float* __restrict__ Ukd,
                  const float* __restrict__ Uco,
                  const float* __restrict__ bias,
                  const short* __restrict__ ucotT,   // may be null
                  float* __restrict__ out)
{
    __shared__ short s[66 * 64];      //  8448 B
    __shared__ short p[64 * 72];      //  9216 B

    const int tid = threadIdx.x;

    const int bid  = blockIdx.x;              // 8192 = 2b * 64h * 64w
    const int slot = bid & 7;
    const int idx  = bid >> 3;                // 1024 per slot
    const int b    = idx >> 9;
    const int rem  = idx & 511;
    const int h    = slot * 8 + (rem >> 6);
    const int w    = rem & 63;

    const short* colp[9];
    bool valid[9];
#pragma unroll
    for (int kh = 0; kh < 3; ++kh) {
#pragma unroll
        for (int kw = 0; kw < 3; ++kw) {
            int hh = h + kh - 1, ww = w + kw - 1;
            bool v = ((unsigned)hh < 64u) && ((unsigned)ww < 64u);
            valid[kh * 3 + kw] = v;
            long base = v ? ((long)(b * 262144 + hh * 4096 + ww * 64) << 6) : 0;
            colp[kh * 3 + kw] = t + base;
        }
    }

    // ---- phase A: hw-conv. thread owns r-quad rq (fixed), iterates sd ----
    const int rq = tid & 15;                  // r = 4*rq .. 4*rq+3
    float4 W[9];
    {
        float4 a[3], c[3];
#pragma unroll
        for (int k = 0; k < 3; ++k) {
            a[k] = *(const float4*)&Ukh[k * 64 + 4 * rq];
            c[k] = *(const float4*)&Ukw[k * 64 + 4 * rq];
        }
#pragma unroll
        for (int kh = 0; kh < 3; ++kh)
#pragma unroll
            for (int kw = 0; kw < 3; ++kw) {
                int kk = kh * 3 + kw;
                float m = valid[kk] ? 1.f : 0.f;
                W[kk].x = a[kh].x * c[kw].x * m;
                W[kk].y = a[kh].y * c[kw].y * m;
                W[kk].z = a[kh].z * c[kw].z * m;
                W[kk].w = a[kh].w * c[kw].w * m;
            }
    }

    // zero edge rows sd=0 (d=-1) and sd=65 (d=64)
    if (tid < 32) {
        int sd = (tid < 16) ? 0 : 65;
        int rr = tid & 15;
        uint2 z; z.x = 0u; z.y = 0u;
        *(uint2*)&s[sd * 64 + 4 * rr] = z;
    }

    // main: 1024 in-bounds items = exactly 4/thread, software-pipelined
    {
        const int off0 = (tid >> 4) * 64 + 4 * rq;
        uint2 cur[9];
#pragma unroll
        for (int kk = 0; kk < 9; ++kk)
            cur[kk] = *(const uint2*)(colp[kk] + off0);

#pragma unroll
        for (int j = 0; j < 4; ++j) {
            uint2 nxt[9];
            if (j < 3) {
#pragma unroll
                for (int kk = 0; kk < 9; ++kk)
                    nxt[kk] = *(const uint2*)(colp[kk] + off0 + 1024 * (j + 1));
            }
            float a0 = 0.f, a1 = 0.f, a2 = 0.f, a3 = 0.f;
#pragma unroll
            for (int kk = 0; kk < 9; ++kk) {
                uint2 uu = cur[kk];
                a0 += W[kk].x * b2f_lo(uu.x);
                a1 += W[kk].y * b2f_hi(uu.x);
                a2 += W[kk].z * b2f_lo(uu.y);
                a3 += W[kk].w * b2f_hi(uu.y);
            }
            int sd = 1 + (tid >> 4) + 16 * j;
            uint2 o; o.x = pack2(a0, a1); o.y = pack2(a2, a3);
            *(uint2*)&s[sd * 64 + 4 * rq] = o;
            if (j < 3) {
#pragma unroll
                for (int kk = 0; kk < 9; ++kk) cur[kk] = nxt[kk];
            }
        }
    }
    __syncthreads();

    // ---- phase B: d-conv into p (stride 72) ----
    {
        float4 Wd[3];
#pragma unroll
        for (int k = 0; k < 3; ++k)
            Wd[k] = *(const float4*)&Ukd[k * 64 + 4 * rq];
        for (int u = tid; u < 64 * 16; u += 256) {
            int d = u >> 4;
            float a0 = 0.f, a1 = 0.f, a2 = 0.f, a3 = 0.f;
#pragma unroll
            for (int k = 0; k < 3; ++k) {
                uint2 uu = *(const uint2*)&s[(d + k) * 64 + 4 * rq];
                a0 += Wd[k].x * b2f_lo(uu.x);
                a1 += Wd[k].y * b2f_hi(uu.x);
                a2 += Wd[k].z * b2f_lo(uu.y);
                a3 += Wd[k].w * b2f_hi(uu.y);
            }
            uint2 o; o.x = pack2(a0, a1); o.y = pack2(a2, a3);
            *(uint2*)&p[d * 72 + 4 * rq] = o;
        }
    }
    __syncthreads();

    // ---- phase C: out GEMM + bias + store. B-frags from global (L2-hit) ----
    {
        const int lane = tid & 63, wv = tid >> 6;
        const int l15 = lane & 15, quad = lane >> 4;
        short8 afr0 = *(const short8*)&p[(wv * 16 + l15) * 72 + quad * 8];
        short8 afr1 = *(const short8*)&p[(wv * 16 + l15) * 72 + 32 + quad * 8];
        f32x4 acc[4] = {};
#pragma unroll
        for (int nt = 0; nt < 4; ++nt) {
            const int co = nt * 16 + l15;
            short8 b0, b1;
            if (ucotT) {
                b0 = *(const short8*)&ucotT[co * 64 + quad * 8];
                b1 = *(const short8*)&ucotT[co * 64 + 32 + quad * 8];
            } else {
                // cold path (never taken when workspace has the 12KB tail)
#pragma unroll
                for (int j = 0; j < 8; ++j) {
                    b0[j] = f2b(Uco[(quad * 8 + j) * 64 + co]);
                    b1[j] = f2b(Uco[(32 + quad * 8 + j) * 64 + co]);
                }
            }
            acc[nt] = __builtin_amdgcn_mfma_f32_16x16x32_bf16(afr0, b0, acc[nt], 0, 0, 0);
            acc[nt] = __builtin_amdgcn_mfma_f32_16x16x32_bf16(afr1, b1, acc[nt], 0, 0, 0);
        }
#pragma unroll
        for (int nt = 0; nt < 4; ++nt) {
            int co = nt * 16 + l15;
            float bs = bias[co];
            int d = wv * 16 + quad * 4;
            float4 o;
            o.x = acc[nt][0] + bs; o.y = acc[nt][1] + bs;
            o.z = acc[nt][2] + bs; o.w = acc[nt][3] + bs;
            long addr = ((long)(b * 64 + co) << 18) + (h << 12) + (w << 6) + d;
            *(float4*)&out[addr] = o;
        }
    }
}

// ============================================================================
// Fallback (fused kernel) if workspace is too small for t.
// ============================================================================
#define NTH 512
#define NPADP 656
#define SMEM_BYTES ((NPADP*32 + NPADP*32 + 432*32 + 64*32 + 64*64)*2 + 576*4)

__global__ __launch_bounds__(NTH)
void cpd_conv3d_fused_fb(const float* __restrict__ x,
                         const float* __restrict__ Ukh,
                         const float* __restrict__ Ukw,
                         const float* __restrict__ Ukd,
                         const float* __restrict__ Ucin,
                         const float* __restrict__ Uco,
                         const float* __restrict__ bias,
                         float* __restrict__ out)
{
    extern __shared__ char smem[];
    short* xs   = (short*)smem;
    short* t0   = xs   + NPADP*32;
    short* t1   = t0   + NPADP*32;
    short* uct  = t1   + 432*32;
    short* ucot = uct  + 64*32;
    float* ukf  = (float*)(ucot + 64*64);

    const int tid  = threadIdx.x;
    const int lane = tid & 63;
    const int wv   = tid >> 6;
    const int l15  = lane & 15;
    const int quad = lane >> 4;
    const int rg   = tid & 3;

    const int bid = blockIdx.x;
    const int dt = bid & 3, wt = (bid >> 2) & 15, ht = (bid >> 6) & 15, b = bid >> 10;
    const int h0 = ht * 4, w0 = wt * 4, d0 = dt * 16;

    for (int i = tid; i < 576; i += NTH) {
        float v = (i < 192) ? Ukh[i] : (i < 384 ? Ukw[i - 192] : Ukd[i - 384]);
        ukf[i] = v;
    }
    for (int i = tid; i < 2048; i += NTH) {
        int r = i >> 5, c = i & 31;
        uct[i] = f2b(Ucin[c * 64 + r]);
    }
    for (int i = tid; i < 4096; i += NTH) {
        int co = i >> 6, r = i & 63;
        ucot[i] = f2b(Uco[r * 64 + co]);
    }
    for (int i = tid; i < NPADP * 32; i += NTH) {
        int pp = i >> 5, c = i & 31;
        float v = 0.f;
        if (pp < 648) {
            int ph = pp / 108, rem = pp - ph * 108;
            int pw = rem / 18, pd = rem - pw * 18;
            int gh = h0 + ph - 1, gw = w0 + pw - 1, gd = d0 + pd - 1;
            if ((unsigned)gh < 64u && (unsigned)gw < 64u && (unsigned)gd < 64u)
                v = x[((long)(b * 32 + c) << 18) + (gh << 12) + (gw << 6) + gd];
        }
        xs[i] = f2b(v);
    }
    __syncthreads();

    f32x4 acc[8] = {};

    for (int pass = 0; pass < 2; ++pass) {
        const int rbase = pass * 32;
        {
            const int nt = wv & 1;
            short8 bfrag = *(const short8*)&uct[(rbase + nt * 16 + l15) * 32 + quad * 8];
            for (int mt = (wv >> 1); mt <= 40; mt += 4) {
                short8 afrag = *(const short8*)&xs[(mt * 16 + l15) * 32 + quad * 8];
                f32x4 c = {};
                c = __builtin_amdgcn_mfma_f32_16x16x32_bf16(afrag, bfrag, c, 0, 0, 0);
                const int col = nt * 16 + l15;
#pragma unroll
                for (int i2 = 0; i2 < 4; ++i2)
                    t0[(mt * 16 + quad * 4 + i2) * 32 + col] = f2b(c[i2]);
            }
        }
        __syncthreads();
        {
            float wh[3][8];
#pragma unroll
            for (int k = 0; k < 3; ++k) {
                const float4* pp_ = (const float4*)&ukf[k * 64 + rbase + rg * 8];
                float4 u0 = pp_[0], u1 = pp_[1];
                wh[k][0]=u0.x; wh[k][1]=u0.y; wh[k][2]=u0.z; wh[k][3]=u0.w;
                wh[k][4]=u1.x; wh[k][5]=u1.y; wh[k][6]=u1.z; wh[k][7]=u1.w;
            }
            for (int item = tid; item < 1728; item += NTH) {
                int q = item >> 2;
                float v[8] = {};
#pragma unroll
                for (int k = 0; k < 3; ++k) {
                    short8 sv = *(const short8*)&t0[(q + k * 108) * 32 + rg * 8];
#pragma unroll
                    for (int j = 0; j < 8; ++j) v[j] += wh[k][j] * b2f(sv[j]);
                }
                short8 o;
#pragma unroll
                for (int j = 0; j < 8; ++j) o[j] = f2b(v[j]);
                *(short8*)&t1[q * 32 + rg * 8] = o;
            }
        }
        __syncthreads();
        {
            float ww[3][8];
#pragma unroll
            for (int k = 0; k < 3; ++k) {
                const float4* pp_ = (const float4*)&ukf[(3 + k) * 64 + rbase + rg * 8];
                float4 u0 = pp_[0], u1 = pp_[1];
                ww[k][0]=u0.x; ww[k][1]=u0.y; ww[k][2]=u0.z; ww[k][3]=u0.w;
                ww[k][4]=u1.x; ww[k][5]=u1.y; ww[k][6]=u1.z; ww[k][7]=u1.w;
            }
            for (int item = tid; item < 1152; item += NTH) {
                int q2 = item >> 2;
                int oh = q2 / 72;
                int src = q2 + oh * 36;
                float v[8] = {};
#pragma unroll
                for (int k = 0; k < 3; ++k) {
                    short8 sv = *(const short8*)&t1[(src + k * 18) * 32 + rg * 8];
#pragma unroll
                    for (int j = 0; j < 8; ++j) v[j] += ww[k][j] * b2f(sv[j]);
                }
                short8 o;
#pragma unroll
                for (int j = 0; j < 8; ++j) o[j] = f2b(v[j]);
                *(short8*)&t0[q2 * 32 + rg * 8] = o;
            }
        }
        __syncthreads();
        {
            float wd[3][8];
#pragma unroll
            for (int k = 0; k < 3; ++k) {
                const float4* pp_ = (const float4*)&ukf[(6 + k) * 64 + rbase + rg * 8];
                float4 u0 = pp_[0], u1 = pp_[1];
                wd[k][0]=u0.x; wd[k][1]=u0.y; wd[k][2]=u0.z; wd[k][3]=u0.w;
                wd[k][4]=u1.x; wd[k][5]=u1.y; wd[k][6]=u1.z; wd[k][7]=u1.w;
            }
            for (int item = tid; item < 1024; item += NTH) {
                int pq = item >> 2;
                int src = pq + (pq >> 4) * 2;
                float v[8] = {};
#pragma unroll
                for (int k = 0; k < 3; ++k) {
                    short8 sv = *(const short8*)&t0[(src + k) * 32 + rg * 8];
#pragma unroll
                    for (int j = 0; j < 8; ++j) v[j] += wd[k][j] * b2f(sv[j]);
                }
                short8 o;
#pragma unroll
                for (int j = 0; j < 8; ++j) o[j] = f2b(v[j]);
                *(short8*)&t1[pq * 32 + rg * 8] = o;
            }
        }
        __syncthreads();
        {
            short8 bfr[4];
#pragma unroll
            for (int nt = 0; nt < 4; ++nt)
                bfr[nt] = *(const short8*)&ucot[(nt * 16 + l15) * 64 + rbase + quad * 8];
#pragma unroll
            for (int i = 0; i < 8; ++i) {
                int mt = wv * 2 + (i >> 2), nt = i & 3;
                short8 afr = *(const short8*)&t1[(mt * 16 + l15) * 32 + quad * 8];
                acc[i] = __builtin_amdgcn_mfma_f32_16x16x32_bf16(afr, bfr[nt], acc[i], 0, 0, 0);
            }
        }
    }

#pragma unroll
    for (int i = 0; i < 8; ++i) {
        int mt = wv * 2 + (i >> 2), nt = i & 3;
        int co = nt * 16 + l15;
        int oh = mt >> 2, ow = mt & 3;
        float bs = bias[co];
        float4 o4;
        o4.x = acc[i][0] + bs; o4.y = acc[i][1] + bs;
        o4.z = acc[i][2] + bs; o4.w = acc[i][3] + bs;
        long addr = ((long)(b * 64 + co) << 18) + ((long)(h0 + oh) << 12)
                  + ((w0 + ow) << 6) + (d0 + quad * 4);
        *(float4*)&out[addr] = o4;
    }
}

extern "C" void kernel_launch(void* const* d_in, const int* in_sizes, int n_in,
                              void* d_out, int out_size, void* d_ws, size_t ws_size,
                              hipStream_t stream) {
    const float* x    = (const float*)d_in[0];
    const float* Ukh  = (const float*)d_in[1];
    const float* Ukw  = (const float*)d_in[2];
    const float* Ukd  = (const float*)d_in[3];
    const float* Ucin = (const float*)d_in[4];
    const float* Uco  = (const float*)d_in[5];
    const float* bias = (const float*)d_in[6];
    float* out = (float*)d_out;

    const size_t needT = (size_t)2 * 262144 * 64 * 2;   // 64 MiB for t (bf16)
    const size_t needM = (4096 + 2048) * 2;             // 12 KiB ucotT + ucinT
    if (ws_size >= needT) {
        short* t = (short*)d_ws;
        short* ucotT = nullptr;
        short* ucinT = nullptr;
        if (ws_size >= needT + needM) {
            ucotT = (short*)((char*)d_ws + needT);
            ucinT = ucotT + 4096;
            k0_prep<<<96, 64, 0, stream>>>(Uco, Ucin, ucotT, ucinT);
        }
        k1_channel<<<2048, 256, 0, stream>>>(x, Ucin, ucinT, t);
        k2_conv_gemm<<<8192, 256, 0, stream>>>(t, Ukh, Ukw, Ukd, Uco, bias, ucotT, out);
    } else {
        (void)hipFuncSetAttribute((const void*)cpd_conv3d_fused_fb,
                                  hipFuncAttributeMaxDynamicSharedMemorySize,
                                  SMEM_BYTES);
        cpd_conv3d_fused_fb<<<2048, NTH, SMEM_BYTES, stream>>>(
            x, Ukh, Ukw, Ukd, Ucin, Uco, bias, out);
    }
}

// Round 8
// 264.130 us; speedup vs baseline: 1.0775x; 1.0775x over previous
//
#include <hip/hip_runtime.h>
#include <hip/hip_bf16.h>

typedef __attribute__((ext_vector_type(8))) short short8;
typedef __attribute__((ext_vector_type(4))) float f32x4;

// bf16 helpers (hardware v_cvt_pk_bf16_f32 via HIP intrinsics).
__device__ __forceinline__ float b2f(short s) {
    return __uint_as_float(((unsigned int)(unsigned short)s) << 16);
}
__device__ __forceinline__ float b2f_lo(unsigned u) {      // low bf16 of dword
    return __uint_as_float(u << 16);
}
__device__ __forceinline__ float b2f_hi(unsigned u) {      // high bf16: 1 op
    return __uint_as_float(u & 0xffff0000u);
}
__device__ __forceinline__ short f2b(float f) {
    union { __hip_bfloat16 h; short s; } cv;
    cv.h = __float2bfloat16(f);
    return cv.s;
}
__device__ __forceinline__ unsigned pack2(float a, float b) {
    union { __hip_bfloat162 h; unsigned u; } cv;
    cv.h = __float22bfloat162_rn(make_float2(a, b));
    return cv.u;
}

// ============================================================================
// K0: one-off prep (~2us).
//   ucotT[co][r] = bf16(Uco[r][co])   (4096)  - k2 staging source
//   ucinT[r][c]  = bf16(Ucin[c][r])   (2048)  - k1 MFMA A-operand
// ============================================================================
__global__ __launch_bounds__(64)
void k0_prep(const float* __restrict__ Uco, const float* __restrict__ Ucin,
             short* __restrict__ ucotT, short* __restrict__ ucinT)
{
    const int i = blockIdx.x * 64 + threadIdx.x;    // 0..6143
    if (i < 4096) {
        int co = i >> 6, r = i & 63;
        ucotT[co * 64 + r] = f2b(Uco[r * 64 + co]);
    } else {
        int j = i - 4096;                           // 0..2047
        int r = j >> 5, c = j & 31;
        ucinT[r * 32 + c] = f2b(Ucin[c * 64 + r]);
    }
}

// ============================================================================
// K1 (unchanged): channel contraction as MFMA GEMM.
//   t[sp][r] = sum_c x[c][sp] * Ucin[c][r]
// ============================================================================
__global__ __launch_bounds__(256)
void k1_channel(const float* __restrict__ x,
                const float* __restrict__ Ucin,
                const short* __restrict__ ucinT_g,   // may be null
                short* __restrict__ t)
{
    __shared__ short xs[256 * 32];    // 16 KB  x^T tile, swizzled 16B slots
    __shared__ short uci[64 * 32];    //  4 KB  Ucin^T [r][c], linear

    const int tid = threadIdx.x;
    const int gp0 = blockIdx.x * 256;              // 2048 blocks, same b per block
    const int b   = gp0 >> 18;
    const int sp  = (gp0 & 262143) + tid;
    const float* xp = x + ((long)b << 23) + sp;

    if (ucinT_g) {
        ((short8*)uci)[tid] = ((const short8*)ucinT_g)[tid];
    } else {
        for (int i = tid; i < 2048; i += 256) {
            int r = i >> 5, c = i & 31;
            uci[i] = f2b(Ucin[c * 64 + r]);
        }
    }

    // stage x^T tile: thread owns sp-row tid; 32 coalesced load streams
    {
        float v[32];
#pragma unroll
        for (int c = 0; c < 32; ++c) v[c] = xp[(long)c << 18];
        const int swz = (tid >> 1) & 3;
#pragma unroll
        for (int oct = 0; oct < 4; ++oct) {
            uint4 o;
            o.x = pack2(v[oct * 8 + 0], v[oct * 8 + 1]);
            o.y = pack2(v[oct * 8 + 2], v[oct * 8 + 3]);
            o.z = pack2(v[oct * 8 + 4], v[oct * 8 + 5]);
            o.w = pack2(v[oct * 8 + 6], v[oct * 8 + 7]);
            *(uint4*)&xs[tid * 32 + ((oct ^ swz) << 3)] = o;
        }
    }
    __syncthreads();

    const int lane = tid & 63, wv = tid >> 6;
    const int l15 = lane & 15, quad = lane >> 4;

    short8 afr[4];
#pragma unroll
    for (int mt = 0; mt < 4; ++mt)
        afr[mt] = *(const short8*)&uci[(mt * 16 + l15) * 32 + quad * 8];

    f32x4 acc[4][4] = {};
#pragma unroll
    for (int nt = 0; nt < 4; ++nt) {
        const int srow = wv * 64 + nt * 16 + l15;
        const int slot = quad ^ ((srow >> 1) & 3);
        short8 bfr = *(const short8*)&xs[srow * 32 + (slot << 3)];
#pragma unroll
        for (int mt = 0; mt < 4; ++mt)
            acc[mt][nt] = __builtin_amdgcn_mfma_f32_16x16x32_bf16(
                afr[mt], bfr, acc[mt][nt], 0, 0, 0);
    }

#pragma unroll
    for (int nt = 0; nt < 4; ++nt) {
        const int srow = wv * 64 + nt * 16 + l15;
        short* tb = t + ((size_t)(gp0 + srow) << 6);
#pragma unroll
        for (int mt = 0; mt < 4; ++mt) {
            uint2 o;
            o.x = pack2(acc[mt][nt][0], acc[mt][nt][1]);
            o.y = pack2(acc[mt][nt][2], acc[mt][nt][3]);
            *(uint2*)&tb[mt * 16 + quad * 4] = o;
        }
    }
}

// ============================================================================
// K2 (round-8): round-6 structure (best measured: LDS ucot staging kept —
// it hides under phase-A latency; round-7's global B-frags cost 20us on the
// post-barrier critical path) + depth-2 phase-A prefetch: batches j+1 AND
// j+2 in flight while computing batch j (3 named reg buffers, full unroll).
//   phase A: hw-conv -> s[66][64]
//   phase B: d-conv -> p[64][72]
//   phase C: out GEMM M=64(d) N=64(co) K=64(r) + bias
// ============================================================================
__global__ __launch_bounds__(256)
void k2_conv_gemm(const short* __restrict__ t,
                  const float* __restrict__ Ukh,
                  const float* __restrict__ Ukw,
                  const float* __restrict__ Ukd,
                  const float* __restrict__ Uco,
                  const float* __restrict__ bias,
                  const short* __restrict__ ucotT,   // may be null
                  float* __restrict__ out)
{
    __shared__ short s[66 * 64];      //  8448 B
    __shared__ short p[64 * 72];      //  9216 B
    __shared__ short ucot[64 * 72];   //  9216 B   Uco^T, padded stride

    const int tid = threadIdx.x;

    const int bid  = blockIdx.x;              // 8192 = 2b * 64h * 64w
    const int slot = bid & 7;
    const int idx  = bid >> 3;                // 1024 per slot
    const int b    = idx >> 9;
    const int rem  = idx & 511;
    const int h    = slot * 8 + (rem >> 6);
    const int w    = rem & 63;

    const short* colp[9];
    bool valid[9];
#pragma unroll
    for (int kh = 0; kh < 3; ++kh) {
#pragma unroll
        for (int kw = 0; kw < 3; ++kw) {
            int hh = h + kh - 1, ww = w + kw - 1;
            bool v = ((unsigned)hh < 64u) && ((unsigned)ww < 64u);
            valid[kh * 3 + kw] = v;
            long base = v ? ((long)(b * 262144 + hh * 4096 + ww * 64) << 6) : 0;
            colp[kh * 3 + kw] = t + base;
        }
    }

    // stage Uco^T (overlaps with phase-A load latency — keep in LDS)
    if (ucotT) {
        for (int i = tid; i < 512; i += 256) {
            int co = i >> 3, rb = i & 7;
            short8 v = *(const short8*)&ucotT[co * 64 + rb * 8];
            *(short8*)&ucot[co * 72 + rb * 8] = v;
        }
    } else {
        for (int i = tid; i < 4096; i += 256) {
            int r = i >> 6, co = i & 63;
            ucot[co * 72 + r] = f2b(Uco[i]);
        }
    }

    // ---- phase A: hw-conv. thread owns r-quad rq (fixed), iterates sd ----
    const int rq = tid & 15;                  // r = 4*rq .. 4*rq+3
    float4 W[9];
    {
        float4 a[3], c[3];
#pragma unroll
        for (int k = 0; k < 3; ++k) {
            a[k] = *(const float4*)&Ukh[k * 64 + 4 * rq];
            c[k] = *(const float4*)&Ukw[k * 64 + 4 * rq];
        }
#pragma unroll
        for (int kh = 0; kh < 3; ++kh)
#pragma unroll
            for (int kw = 0; kw < 3; ++kw) {
                int kk = kh * 3 + kw;
                float m = valid[kk] ? 1.f : 0.f;
                W[kk].x = a[kh].x * c[kw].x * m;
                W[kk].y = a[kh].y * c[kw].y * m;
                W[kk].z = a[kh].z * c[kw].z * m;
                W[kk].w = a[kh].w * c[kw].w * m;
            }
    }

    // zero edge rows sd=0 (d=-1) and sd=65 (d=64)
    if (tid < 32) {
        int sd = (tid < 16) ? 0 : 65;
        int rr = tid & 15;
        uint2 z; z.x = 0u; z.y = 0u;
        *(uint2*)&s[sd * 64 + 4 * rr] = z;
    }

    // main: 1024 in-bounds items = exactly 4/thread, depth-2 pipelined.
#define PA_COMPUTE(BUF, J)                                                  \
    {                                                                       \
        float a0 = 0.f, a1 = 0.f, a2 = 0.f, a3 = 0.f;                       \
        _Pragma("unroll")                                                   \
        for (int kk = 0; kk < 9; ++kk) {                                    \
            uint2 uu = BUF[kk];                                             \
            a0 += W[kk].x * b2f_lo(uu.x);                                   \
            a1 += W[kk].y * b2f_hi(uu.x);                                   \
            a2 += W[kk].z * b2f_lo(uu.y);                                   \
            a3 += W[kk].w * b2f_hi(uu.y);                                   \
        }                                                                   \
        int sd = 1 + (tid >> 4) + 16 * (J);                                 \
        uint2 o; o.x = pack2(a0, a1); o.y = pack2(a2, a3);                  \
        *(uint2*)&s[sd * 64 + 4 * rq] = o;                                  \
    }

    {
        const int off0 = (tid >> 4) * 64 + 4 * rq;
        uint2 bA[9], bB[9], bC[9];
#pragma unroll
        for (int kk = 0; kk < 9; ++kk) bA[kk] = *(const uint2*)(colp[kk] + off0);
#pragma unroll
        for (int kk = 0; kk < 9; ++kk) bB[kk] = *(const uint2*)(colp[kk] + off0 + 1024);

        // j=0: issue batch 2, compute batch 0
#pragma unroll
        for (int kk = 0; kk < 9; ++kk) bC[kk] = *(const uint2*)(colp[kk] + off0 + 2048);
        PA_COMPUTE(bA, 0)
        // j=1: issue batch 3 (reuse bA regs), compute batch 1
#pragma unroll
        for (int kk = 0; kk < 9; ++kk) bA[kk] = *(const uint2*)(colp[kk] + off0 + 3072);
        PA_COMPUTE(bB, 1)
        // j=2: compute batch 2
        PA_COMPUTE(bC, 2)
        // j=3: compute batch 3
        PA_COMPUTE(bA, 3)
    }
#undef PA_COMPUTE
    __syncthreads();

    // ---- phase B: d-conv into p (stride 72) ----
    {
        float4 Wd[3];
#pragma unroll
        for (int k = 0; k < 3; ++k)
            Wd[k] = *(const float4*)&Ukd[k * 64 + 4 * rq];
        for (int u = tid; u < 64 * 16; u += 256) {
            int d = u >> 4;
            float a0 = 0.f, a1 = 0.f, a2 = 0.f, a3 = 0.f;
#pragma unroll
            for (int k = 0; k < 3; ++k) {
                uint2 uu = *(const uint2*)&s[(d + k) * 64 + 4 * rq];
                a0 += Wd[k].x * b2f_lo(uu.x);
                a1 += Wd[k].y * b2f_hi(uu.x);
                a2 += Wd[k].z * b2f_lo(uu.y);
                a3 += Wd[k].w * b2f_hi(uu.y);
            }
            uint2 o; o.x = pack2(a0, a1); o.y = pack2(a2, a3);
            *(uint2*)&p[d * 72 + 4 * rq] = o;
        }
    }
    __syncthreads();

    // ---- phase C: out GEMM + bias + store ----
    {
        const int lane = tid & 63, wv = tid >> 6;
        const int l15 = lane & 15, quad = lane >> 4;
        short8 afr0 = *(const short8*)&p[(wv * 16 + l15) * 72 + quad * 8];
        short8 afr1 = *(const short8*)&p[(wv * 16 + l15) * 72 + 32 + quad * 8];
        f32x4 acc[4] = {};
#pragma unroll
        for (int nt = 0; nt < 4; ++nt) {
            short8 b0 = *(const short8*)&ucot[(nt * 16 + l15) * 72 + quad * 8];
            short8 b1 = *(const short8*)&ucot[(nt * 16 + l15) * 72 + 32 + quad * 8];
            acc[nt] = __builtin_amdgcn_mfma_f32_16x16x32_bf16(afr0, b0, acc[nt], 0, 0, 0);
            acc[nt] = __builtin_amdgcn_mfma_f32_16x16x32_bf16(afr1, b1, acc[nt], 0, 0, 0);
        }
#pragma unroll
        for (int nt = 0; nt < 4; ++nt) {
            int co = nt * 16 + l15;
            float bs = bias[co];
            int d = wv * 16 + quad * 4;
            float4 o;
            o.x = acc[nt][0] + bs; o.y = acc[nt][1] + bs;
            o.z = acc[nt][2] + bs; o.w = acc[nt][3] + bs;
            long addr = ((long)(b * 64 + co) << 18) + (h << 12) + (w << 6) + d;
            *(float4*)&out[addr] = o;
        }
    }
}

// ============================================================================
// Fallback (fused kernel) if workspace is too small for t.
// ============================================================================
#define NTH 512
#define NPADP 656
#define SMEM_BYTES ((NPADP*32 + NPADP*32 + 432*32 + 64*32 + 64*64)*2 + 576*4)

__global__ __launch_bounds__(NTH)
void cpd_conv3d_fused_fb(const float* __restrict__ x,
                         const float* __restrict__ Ukh,
                         const float* __restrict__ Ukw,
                         const float* __restrict__ Ukd,
                         const float* __restrict__ Ucin,
                         const float* __restrict__ Uco,
                         const float* __restrict__ bias,
                         float* __restrict__ out)
{
    extern __shared__ char smem[];
    short* xs   = (short*)smem;
    short* t0   = xs   + NPADP*32;
    short* t1   = t0   + NPADP*32;
    short* uct  = t1   + 432*32;
    short* ucot = uct  + 64*32;
    float* ukf  = (float*)(ucot + 64*64);

    const int tid  = threadIdx.x;
    const int lane = tid & 63;
    const int wv   = tid >> 6;
    const int l15  = lane & 15;
    const int quad = lane >> 4;
    const int rg   = tid & 3;

    const int bid = blockIdx.x;
    const int dt = bid & 3, wt = (bid >> 2) & 15, ht = (bid >> 6) & 15, b = bid >> 10;
    const int h0 = ht * 4, w0 = wt * 4, d0 = dt * 16;

    for (int i = tid; i < 576; i += NTH) {
        float v = (i < 192) ? Ukh[i] : (i < 384 ? Ukw[i - 192] : Ukd[i - 384]);
        ukf[i] = v;
    }
    for (int i = tid; i < 2048; i += NTH) {
        int r = i >> 5, c = i & 31;
        uct[i] = f2b(Ucin[c * 64 + r]);
    }
    for (int i = tid; i < 4096; i += NTH) {
        int co = i >> 6, r = i & 63;
        ucot[i] = f2b(Uco[r * 64 + co]);
    }
    for (int i = tid; i < NPADP * 32; i += NTH) {
        int pp = i >> 5, c = i & 31;
        float v = 0.f;
        if (pp < 648) {
            int ph = pp / 108, rem = pp - ph * 108;
            int pw = rem / 18, pd = rem - pw * 18;
            int gh = h0 + ph - 1, gw = w0 + pw - 1, gd = d0 + pd - 1;
            if ((unsigned)gh < 64u && (unsigned)gw < 64u && (unsigned)gd < 64u)
                v = x[((long)(b * 32 + c) << 18) + (gh << 12) + (gw << 6) + gd];
        }
        xs[i] = f2b(v);
    }
    __syncthreads();

    f32x4 acc[8] = {};

    for (int pass = 0; pass < 2; ++pass) {
        const int rbase = pass * 32;
        {
            const int nt = wv & 1;
            short8 bfrag = *(const short8*)&uct[(rbase + nt * 16 + l15) * 32 + quad * 8];
            for (int mt = (wv >> 1); mt <= 40; mt += 4) {
                short8 afrag = *(const short8*)&xs[(mt * 16 + l15) * 32 + quad * 8];
                f32x4 c = {};
                c = __builtin_amdgcn_mfma_f32_16x16x32_bf16(afrag, bfrag, c, 0, 0, 0);
                const int col = nt * 16 + l15;
#pragma unroll
                for (int i2 = 0; i2 < 4; ++i2)
                    t0[(mt * 16 + quad * 4 + i2) * 32 + col] = f2b(c[i2]);
            }
        }
        __syncthreads();
        {
            float wh[3][8];
#pragma unroll
            for (int k = 0; k < 3; ++k) {
                const float4* pp_ = (const float4*)&ukf[k * 64 + rbase + rg * 8];
                float4 u0 = pp_[0], u1 = pp_[1];
                wh[k][0]=u0.x; wh[k][1]=u0.y; wh[k][2]=u0.z; wh[k][3]=u0.w;
                wh[k][4]=u1.x; wh[k][5]=u1.y; wh[k][6]=u1.z; wh[k][7]=u1.w;
            }
            for (int item = tid; item < 1728; item += NTH) {
                int q = item >> 2;
                float v[8] = {};
#pragma unroll
                for (int k = 0; k < 3; ++k) {
                    short8 sv = *(const short8*)&t0[(q + k * 108) * 32 + rg * 8];
#pragma unroll
                    for (int j = 0; j < 8; ++j) v[j] += wh[k][j] * b2f(sv[j]);
                }
                short8 o;
#pragma unroll
                for (int j = 0; j < 8; ++j) o[j] = f2b(v[j]);
                *(short8*)&t1[q * 32 + rg * 8] = o;
            }
        }
        __syncthreads();
        {
            float ww[3][8];
#pragma unroll
            for (int k = 0; k < 3; ++k) {
                const float4* pp_ = (const float4*)&ukf[(3 + k) * 64 + rbase + rg * 8];
                float4 u0 = pp_[0], u1 = pp_[1];
                ww[k][0]=u0.x; ww[k][1]=u0.y; ww[k][2]=u0.z; ww[k][3]=u0.w;
                ww[k][4]=u1.x; ww[k][5]=u1.y; ww[k][6]=u1.z; ww[k][7]=u1.w;
            }
            for (int item = tid; item < 1152; item += NTH) {
                int q2 = item >> 2;
                int oh = q2 / 72;
                int src = q2 + oh * 36;
                float v[8] = {};
#pragma unroll
                for (int k = 0; k < 3; ++k) {
                    short8 sv = *(const short8*)&t1[(src + k * 18) * 32 + rg * 8];
#pragma unroll
                    for (int j = 0; j < 8; ++j) v[j] += ww[k][j] * b2f(sv[j]);
                }
                short8 o;
#pragma unroll
                for (int j = 0; j < 8; ++j) o[j] = f2b(v[j]);
                *(short8*)&t0[q2 * 32 + rg * 8] = o;
            }
        }
        __syncthreads();
        {
            float wd[3][8];
#pragma unroll
            for (int k = 0; k < 3; ++k) {
                const float4* pp_ = (const float4*)&ukf[(6 + k) * 64 + rbase + rg * 8];
                float4 u0 = pp_[0], u1 = pp_[1];
                wd[k][0]=u0.x; wd[k][1]=u0.y; wd[k][2]=u0.z; wd[k][3]=u0.w;
                wd[k][4]=u1.x; wd[k][5]=u1.y; wd[k][6]=u1.z; wd[k][7]=u1.w;
            }
            for (int item = tid; item < 1024; item += NTH) {
                int pq = item >> 2;
                int src = pq + (pq >> 4) * 2;
                float v[8] = {};
#pragma unroll
                for (int k = 0; k < 3; ++k) {
                    short8 sv = *(const short8*)&t0[(src + k) * 32 + rg * 8];
#pragma unroll
                    for (int j = 0; j < 8; ++j) v[j] += wd[k][j] * b2f(sv[j]);
                }
                short8 o;
#pragma unroll
                for (int j = 0; j < 8; ++j) o[j] = f2b(v[j]);
                *(short8*)&t1[pq * 32 + rg * 8] = o;
            }
        }
        __syncthreads();
        {
            short8 bfr[4];
#pragma unroll
            for (int nt = 0; nt < 4; ++nt)
                bfr[nt] = *(const short8*)&ucot[(nt * 16 + l15) * 64 + rbase + quad * 8];
#pragma unroll
            for (int i = 0; i < 8; ++i) {
                int mt = wv * 2 + (i >> 2), nt = i & 3;
                short8 afr = *(const short8*)&t1[(mt * 16 + l15) * 32 + quad * 8];
                acc[i] = __builtin_amdgcn_mfma_f32_16x16x32_bf16(afr, bfr[nt], acc[i], 0, 0, 0);
            }
        }
    }

#pragma unroll
    for (int i = 0; i < 8; ++i) {
        int mt = wv * 2 + (i >> 2), nt = i & 3;
        int co = nt * 16 + l15;
        int oh = mt >> 2, ow = mt & 3;
        float bs = bias[co];
        float4 o4;
        o4.x = acc[i][0] + bs; o4.y = acc[i][1] + bs;
        o4.z = acc[i][2] + bs; o4.w = acc[i][3] + bs;
        long addr = ((long)(b * 64 + co) << 18) + ((long)(h0 + oh) << 12)
                  + ((w0 + ow) << 6) + (d0 + quad * 4);
        *(float4*)&out[addr] = o4;
    }
}

extern "C" void kernel_launch(void* const* d_in, const int* in_sizes, int n_in,
                              void* d_out, int out_size, void* d_ws, size_t ws_size,
                              hipStream_t stream) {
    const float* x    = (const float*)d_in[0];
    const float* Ukh  = (const float*)d_in[1];
    const float* Ukw  = (const float*)d_in[2];
    const float* Ukd  = (const float*)d_in[3];
    const float* Ucin = (const float*)d_in[4];
    const float* Uco  = (const float*)d_in[5];
    const float* bias = (const float*)d_in[6];
    float* out = (float*)d_out;

    const size_t needT = (size_t)2 * 262144 * 64 * 2;   // 64 MiB for t (bf16)
    const size_t needM = (4096 + 2048) * 2;             // 12 KiB ucotT + ucinT
    if (ws_size >= needT) {
        short* t = (short*)d_ws;
        short* ucotT = nullptr;
        short* ucinT = nullptr;
        if (ws_size >= needT + needM) {
            ucotT = (short*)((char*)d_ws + needT);
            ucinT = ucotT + 4096;
            k0_prep<<<96, 64, 0, stream>>>(Uco, Ucin, ucotT, ucinT);
        }
        k1_channel<<<2048, 256, 0, stream>>>(x, Ucin, ucinT, t);
        k2_conv_gemm<<<8192, 256, 0, stream>>>(t, Ukh, Ukw, Ukd, Uco, bias, ucotT, out);
    } else {
        (void)hipFuncSetAttribute((const void*)cpd_conv3d_fused_fb,
                                  hipFuncAttributeMaxDynamicSharedMemorySize,
                                  SMEM_BYTES);
        cpd_conv3d_fused_fb<<<2048, NTH, SMEM_BYTES, stream>>>(
            x, Ukh, Ukw, Ukd, Ucin, Uco, bias, out);
    }
}

// Round 9
// 260.306 us; speedup vs baseline: 1.0933x; 1.0147x over previous
//
#include <hip/hip_runtime.h>
#include <hip/hip_bf16.h>

typedef __attribute__((ext_vector_type(8))) short short8;
typedef __attribute__((ext_vector_type(4))) float f32x4;

// bf16 helpers (hardware v_cvt_pk_bf16_f32 via HIP intrinsics).
__device__ __forceinline__ float b2f(short s) {
    return __uint_as_float(((unsigned int)(unsigned short)s) << 16);
}
__device__ __forceinline__ float b2f_lo(unsigned u) {      // low bf16 of dword
    return __uint_as_float(u << 16);
}
__device__ __forceinline__ float b2f_hi(unsigned u) {      // high bf16: 1 op
    return __uint_as_float(u & 0xffff0000u);
}
__device__ __forceinline__ short f2b(float f) {
    union { __hip_bfloat16 h; short s; } cv;
    cv.h = __float2bfloat16(f);
    return cv.s;
}
__device__ __forceinline__ unsigned pack2(float a, float b) {
    union { __hip_bfloat162 h; unsigned u; } cv;
    cv.h = __float22bfloat162_rn(make_float2(a, b));
    return cv.u;
}

// ============================================================================
// K0: one-off prep (~2us).
//   ucotT[co][r] = bf16(Uco[r][co])   (4096)  - k2 staging source
//   ucinT[r][c]  = bf16(Ucin[c][r])   (2048)  - k1 MFMA A-operand
// ============================================================================
__global__ __launch_bounds__(64)
void k0_prep(const float* __restrict__ Uco, const float* __restrict__ Ucin,
             short* __restrict__ ucotT, short* __restrict__ ucinT)
{
    const int i = blockIdx.x * 64 + threadIdx.x;    // 0..6143
    if (i < 4096) {
        int co = i >> 6, r = i & 63;
        ucotT[co * 64 + r] = f2b(Uco[r * 64 + co]);
    } else {
        int j = i - 4096;                           // 0..2047
        int r = j >> 5, c = j & 31;
        ucinT[r * 32 + c] = f2b(Ucin[c * 64 + r]);
    }
}

// ============================================================================
// K1 (unchanged): channel contraction as MFMA GEMM.
//   t[sp][r] = sum_c x[c][sp] * Ucin[c][r]
// ============================================================================
__global__ __launch_bounds__(256)
void k1_channel(const float* __restrict__ x,
                const float* __restrict__ Ucin,
                const short* __restrict__ ucinT_g,   // may be null
                short* __restrict__ t)
{
    __shared__ short xs[256 * 32];    // 16 KB  x^T tile, swizzled 16B slots
    __shared__ short uci[64 * 32];    //  4 KB  Ucin^T [r][c], linear

    const int tid = threadIdx.x;
    const int gp0 = blockIdx.x * 256;              // 2048 blocks, same b per block
    const int b   = gp0 >> 18;
    const int sp  = (gp0 & 262143) + tid;
    const float* xp = x + ((long)b << 23) + sp;

    if (ucinT_g) {
        ((short8*)uci)[tid] = ((const short8*)ucinT_g)[tid];
    } else {
        for (int i = tid; i < 2048; i += 256) {
            int r = i >> 5, c = i & 31;
            uci[i] = f2b(Ucin[c * 64 + r]);
        }
    }

    // stage x^T tile: thread owns sp-row tid; 32 coalesced load streams
    {
        float v[32];
#pragma unroll
        for (int c = 0; c < 32; ++c) v[c] = xp[(long)c << 18];
        const int swz = (tid >> 1) & 3;
#pragma unroll
        for (int oct = 0; oct < 4; ++oct) {
            uint4 o;
            o.x = pack2(v[oct * 8 + 0], v[oct * 8 + 1]);
            o.y = pack2(v[oct * 8 + 2], v[oct * 8 + 3]);
            o.z = pack2(v[oct * 8 + 4], v[oct * 8 + 5]);
            o.w = pack2(v[oct * 8 + 6], v[oct * 8 + 7]);
            *(uint4*)&xs[tid * 32 + ((oct ^ swz) << 3)] = o;
        }
    }
    __syncthreads();

    const int lane = tid & 63, wv = tid >> 6;
    const int l15 = lane & 15, quad = lane >> 4;

    short8 afr[4];
#pragma unroll
    for (int mt = 0; mt < 4; ++mt)
        afr[mt] = *(const short8*)&uci[(mt * 16 + l15) * 32 + quad * 8];

    f32x4 acc[4][4] = {};
#pragma unroll
    for (int nt = 0; nt < 4; ++nt) {
        const int srow = wv * 64 + nt * 16 + l15;
        const int slot = quad ^ ((srow >> 1) & 3);
        short8 bfr = *(const short8*)&xs[srow * 32 + (slot << 3)];
#pragma unroll
        for (int mt = 0; mt < 4; ++mt)
            acc[mt][nt] = __builtin_amdgcn_mfma_f32_16x16x32_bf16(
                afr[mt], bfr, acc[mt][nt], 0, 0, 0);
    }

#pragma unroll
    for (int nt = 0; nt < 4; ++nt) {
        const int srow = wv * 64 + nt * 16 + l15;
        short* tb = t + ((size_t)(gp0 + srow) << 6);
#pragma unroll
        for (int mt = 0; mt < 4; ++mt) {
            uint2 o;
            o.x = pack2(acc[mt][nt][0], acc[mt][nt][1]);
            o.y = pack2(acc[mt][nt][2], acc[mt][nt][3]);
            *(uint2*)&tb[mt * 16 + quad * 4] = o;
        }
    }
}

// ============================================================================
// K2 (round-9): phase B fused into phase C in registers.
//   phase A: hw-conv -> s[66][64] bf16, XOR-swizzled (byte ^= (row&7)<<4)
//   fused BC: each C-thread computes its own p-row (d = wv*16+l15, 16 r-cols)
//     directly from s: 6 swizzled ds_read_b128 + 48 f32 FMA + 8 cvt_pk,
//     then 8 MFMA + bias + store.  Removes: phase B pass, p buffer (9KB),
//     one __syncthreads, one bf16 round-trip.
//   The fused read pattern (16 lanes at 128B row stride, fixed col) is a
//   16-way bank conflict on linear layout -> the XOR swizzle (T2, G4) makes
//   both A-writes and BC-reads minimum-aliasing.  Ukd staged to LDS (768B,
//   quad-uniform broadcast reads).  ucot LDS staging kept (round-7 lesson:
//   global B-frags after the last barrier cost 20us).
// ============================================================================
__global__ __launch_bounds__(256)
void k2_conv_gemm(const short* __restrict__ t,
                  const float* __restrict__ Ukh,
                  const float* __restrict__ Ukw,
                  const float* __restrict__ Ukd,
                  const float* __restrict__ Uco,
                  const float* __restrict__ bias,
                  const short* __restrict__ ucotT,   // may be null
                  float* __restrict__ out)
{
    __shared__ short s[66 * 64];      //  8448 B  (swizzled)
    __shared__ short ucot[64 * 72];   //  9216 B  Uco^T, padded stride
    __shared__ float ukds[192];       //   768 B  Ukd staged

    const int tid = threadIdx.x;

    const int bid  = blockIdx.x;              // 8192 = 2b * 64h * 64w
    const int slot = bid & 7;
    const int idx  = bid >> 3;                // 1024 per slot
    const int b    = idx >> 9;
    const int rem  = idx & 511;
    const int h    = slot * 8 + (rem >> 6);
    const int w    = rem & 63;

    const short* colp[9];
    bool valid[9];
#pragma unroll
    for (int kh = 0; kh < 3; ++kh) {
#pragma unroll
        for (int kw = 0; kw < 3; ++kw) {
            int hh = h + kh - 1, ww = w + kw - 1;
            bool v = ((unsigned)hh < 64u) && ((unsigned)ww < 64u);
            valid[kh * 3 + kw] = v;
            long base = v ? ((long)(b * 262144 + hh * 4096 + ww * 64) << 6) : 0;
            colp[kh * 3 + kw] = t + base;
        }
    }

    // stage Ukd (768B) — consumed after the barrier
    if (tid < 192) ukds[tid] = Ukd[tid];

    // stage Uco^T (overlaps with phase-A load latency — keep in LDS)
    if (ucotT) {
        for (int i = tid; i < 512; i += 256) {
            int co = i >> 3, rb = i & 7;
            short8 v = *(const short8*)&ucotT[co * 64 + rb * 8];
            *(short8*)&ucot[co * 72 + rb * 8] = v;
        }
    } else {
        for (int i = tid; i < 4096; i += 256) {
            int r = i >> 6, co = i & 63;
            ucot[co * 72 + r] = f2b(Uco[i]);
        }
    }

    // ---- phase A: hw-conv. thread owns r-quad rq (fixed), iterates sd ----
    const int rq = tid & 15;                  // r = 4*rq .. 4*rq+3
    float4 W[9];
    {
        float4 a[3], c[3];
#pragma unroll
        for (int k = 0; k < 3; ++k) {
            a[k] = *(const float4*)&Ukh[k * 64 + 4 * rq];
            c[k] = *(const float4*)&Ukw[k * 64 + 4 * rq];
        }
#pragma unroll
        for (int kh = 0; kh < 3; ++kh)
#pragma unroll
            for (int kw = 0; kw < 3; ++kw) {
                int kk = kh * 3 + kw;
                float m = valid[kk] ? 1.f : 0.f;
                W[kk].x = a[kh].x * c[kw].x * m;
                W[kk].y = a[kh].y * c[kw].y * m;
                W[kk].z = a[kh].z * c[kw].z * m;
                W[kk].w = a[kh].w * c[kw].w * m;
            }
    }

    // zero edge rows sd=0 (d=-1) and sd=65 (d=64), swizzled
    if (tid < 32) {
        int sd = (tid < 16) ? 0 : 65;
        int rr = tid & 15;
        uint2 z; z.x = 0u; z.y = 0u;
        *(uint2*)((char*)s + sd * 128 + ((8 * rr) ^ ((sd & 7) << 4))) = z;
    }

    // main: 1024 in-bounds items = exactly 4/thread, depth-2 pipelined.
#define PA_COMPUTE(BUF, J)                                                  \
    {                                                                       \
        float a0 = 0.f, a1 = 0.f, a2 = 0.f, a3 = 0.f;                       \
        _Pragma("unroll")                                                   \
        for (int kk = 0; kk < 9; ++kk) {                                    \
            uint2 uu = BUF[kk];                                             \
            a0 += W[kk].x * b2f_lo(uu.x);                                   \
            a1 += W[kk].y * b2f_hi(uu.x);                                   \
            a2 += W[kk].z * b2f_lo(uu.y);                                   \
            a3 += W[kk].w * b2f_hi(uu.y);                                   \
        }                                                                   \
        int sd = 1 + (tid >> 4) + 16 * (J);                                 \
        uint2 o; o.x = pack2(a0, a1); o.y = pack2(a2, a3);                  \
        *(uint2*)((char*)s + sd * 128 + ((8 * rq) ^ ((sd & 7) << 4))) = o;  \
    }

    {
        const int off0 = (tid >> 4) * 64 + 4 * rq;
        uint2 bA[9], bB[9], bC[9];
#pragma unroll
        for (int kk = 0; kk < 9; ++kk) bA[kk] = *(const uint2*)(colp[kk] + off0);
#pragma unroll
        for (int kk = 0; kk < 9; ++kk) bB[kk] = *(const uint2*)(colp[kk] + off0 + 1024);

#pragma unroll
        for (int kk = 0; kk < 9; ++kk) bC[kk] = *(const uint2*)(colp[kk] + off0 + 2048);
        PA_COMPUTE(bA, 0)
#pragma unroll
        for (int kk = 0; kk < 9; ++kk) bA[kk] = *(const uint2*)(colp[kk] + off0 + 3072);
        PA_COMPUTE(bB, 1)
        PA_COMPUTE(bC, 2)
        PA_COMPUTE(bA, 3)
    }
#undef PA_COMPUTE
    __syncthreads();

    // ---- fused BC: d-conv in registers + out GEMM + bias + store ----
    {
        const int lane = tid & 63, wv = tid >> 6;
        const int l15 = lane & 15, quad = lane >> 4;
        const int row0 = wv * 16 + l15;       // output d-row this thread owns

        float p0[8] = {}, p1[8] = {};
#pragma unroll
        for (int k = 0; k < 3; ++k) {
            const int row = row0 + k;         // s rows d..d+2  (sd = d+k)
            const int swz = (row & 7) << 4;
            const char* rb = (const char*)s + row * 128;
            short8 sv0 = *(const short8*)(rb + ((quad * 16) ^ swz));
            short8 sv1 = *(const short8*)(rb + ((64 + quad * 16) ^ swz));
            float4 wa = *(const float4*)&ukds[k * 64 + quad * 8];
            float4 wb = *(const float4*)&ukds[k * 64 + quad * 8 + 4];
            float4 wc = *(const float4*)&ukds[k * 64 + 32 + quad * 8];
            float4 wd = *(const float4*)&ukds[k * 64 + 32 + quad * 8 + 4];
            p0[0] += wa.x * b2f(sv0[0]);  p0[1] += wa.y * b2f(sv0[1]);
            p0[2] += wa.z * b2f(sv0[2]);  p0[3] += wa.w * b2f(sv0[3]);
            p0[4] += wb.x * b2f(sv0[4]);  p0[5] += wb.y * b2f(sv0[5]);
            p0[6] += wb.z * b2f(sv0[6]);  p0[7] += wb.w * b2f(sv0[7]);
            p1[0] += wc.x * b2f(sv1[0]);  p1[1] += wc.y * b2f(sv1[1]);
            p1[2] += wc.z * b2f(sv1[2]);  p1[3] += wc.w * b2f(sv1[3]);
            p1[4] += wd.x * b2f(sv1[4]);  p1[5] += wd.y * b2f(sv1[5]);
            p1[6] += wd.z * b2f(sv1[6]);  p1[7] += wd.w * b2f(sv1[7]);
        }
        union { short8 s8; unsigned u[4]; } a0c, a1c;
        a0c.u[0] = pack2(p0[0], p0[1]); a0c.u[1] = pack2(p0[2], p0[3]);
        a0c.u[2] = pack2(p0[4], p0[5]); a0c.u[3] = pack2(p0[6], p0[7]);
        a1c.u[0] = pack2(p1[0], p1[1]); a1c.u[1] = pack2(p1[2], p1[3]);
        a1c.u[2] = pack2(p1[4], p1[5]); a1c.u[3] = pack2(p1[6], p1[7]);
        short8 afr0 = a0c.s8, afr1 = a1c.s8;

        f32x4 acc[4] = {};
#pragma unroll
        for (int nt = 0; nt < 4; ++nt) {
            short8 b0 = *(const short8*)&ucot[(nt * 16 + l15) * 72 + quad * 8];
            short8 b1 = *(const short8*)&ucot[(nt * 16 + l15) * 72 + 32 + quad * 8];
            acc[nt] = __builtin_amdgcn_mfma_f32_16x16x32_bf16(afr0, b0, acc[nt], 0, 0, 0);
            acc[nt] = __builtin_amdgcn_mfma_f32_16x16x32_bf16(afr1, b1, acc[nt], 0, 0, 0);
        }
#pragma unroll
        for (int nt = 0; nt < 4; ++nt) {
            int co = nt * 16 + l15;
            float bs = bias[co];
            int d = wv * 16 + quad * 4;
            float4 o;
            o.x = acc[nt][0] + bs; o.y = acc[nt][1] + bs;
            o.z = acc[nt][2] + bs; o.w = acc[nt][3] + bs;
            long addr = ((long)(b * 64 + co) << 18) + (h << 12) + (w << 6) + d;
            *(float4*)&out[addr] = o;
        }
    }
}

// ============================================================================
// Fallback (fused kernel) if workspace is too small for t.
// ============================================================================
#define NTH 512
#define NPADP 656
#define SMEM_BYTES ((NPADP*32 + NPADP*32 + 432*32 + 64*32 + 64*64)*2 + 576*4)

__global__ __launch_bounds__(NTH)
void cpd_conv3d_fused_fb(const float* __restrict__ x,
                         const float* __restrict__ Ukh,
                         const float* __restrict__ Ukw,
                         const float* __restrict__ Ukd,
                         const float* __restrict__ Ucin,
                         const float* __restrict__ Uco,
                         const float* __restrict__ bias,
                         float* __restrict__ out)
{
    extern __shared__ char smem[];
    short* xs   = (short*)smem;
    short* t0   = xs   + NPADP*32;
    short* t1   = t0   + NPADP*32;
    short* uct  = t1   + 432*32;
    short* ucot = uct  + 64*32;
    float* ukf  = (float*)(ucot + 64*64);

    const int tid  = threadIdx.x;
    const int lane = tid & 63;
    const int wv   = tid >> 6;
    const int l15  = lane & 15;
    const int quad = lane >> 4;
    const int rg   = tid & 3;

    const int bid = blockIdx.x;
    const int dt = bid & 3, wt = (bid >> 2) & 15, ht = (bid >> 6) & 15, b = bid >> 10;
    const int h0 = ht * 4, w0 = wt * 4, d0 = dt * 16;

    for (int i = tid; i < 576; i += NTH) {
        float v = (i < 192) ? Ukh[i] : (i < 384 ? Ukw[i - 192] : Ukd[i - 384]);
        ukf[i] = v;
    }
    for (int i = tid; i < 2048; i += NTH) {
        int r = i >> 5, c = i & 31;
        uct[i] = f2b(Ucin[c * 64 + r]);
    }
    for (int i = tid; i < 4096; i += NTH) {
        int co = i >> 6, r = i & 63;
        ucot[i] = f2b(Uco[r * 64 + co]);
    }
    for (int i = tid; i < NPADP * 32; i += NTH) {
        int pp = i >> 5, c = i & 31;
        float v = 0.f;
        if (pp < 648) {
            int ph = pp / 108, rem = pp - ph * 108;
            int pw = rem / 18, pd = rem - pw * 18;
            int gh = h0 + ph - 1, gw = w0 + pw - 1, gd = d0 + pd - 1;
            if ((unsigned)gh < 64u && (unsigned)gw < 64u && (unsigned)gd < 64u)
                v = x[((long)(b * 32 + c) << 18) + (gh << 12) + (gw << 6) + gd];
        }
        xs[i] = f2b(v);
    }
    __syncthreads();

    f32x4 acc[8] = {};

    for (int pass = 0; pass < 2; ++pass) {
        const int rbase = pass * 32;
        {
            const int nt = wv & 1;
            short8 bfrag = *(const short8*)&uct[(rbase + nt * 16 + l15) * 32 + quad * 8];
            for (int mt = (wv >> 1); mt <= 40; mt += 4) {
                short8 afrag = *(const short8*)&xs[(mt * 16 + l15) * 32 + quad * 8];
                f32x4 c = {};
                c = __builtin_amdgcn_mfma_f32_16x16x32_bf16(afrag, bfrag, c, 0, 0, 0);
                const int col = nt * 16 + l15;
#pragma unroll
                for (int i2 = 0; i2 < 4; ++i2)
                    t0[(mt * 16 + quad * 4 + i2) * 32 + col] = f2b(c[i2]);
            }
        }
        __syncthreads();
        {
            float wh[3][8];
#pragma unroll
            for (int k = 0; k < 3; ++k) {
                const float4* pp_ = (const float4*)&ukf[k * 64 + rbase + rg * 8];
                float4 u0 = pp_[0], u1 = pp_[1];
                wh[k][0]=u0.x; wh[k][1]=u0.y; wh[k][2]=u0.z; wh[k][3]=u0.w;
                wh[k][4]=u1.x; wh[k][5]=u1.y; wh[k][6]=u1.z; wh[k][7]=u1.w;
            }
            for (int item = tid; item < 1728; item += NTH) {
                int q = item >> 2;
                float v[8] = {};
#pragma unroll
                for (int k = 0; k < 3; ++k) {
                    short8 sv = *(const short8*)&t0[(q + k * 108) * 32 + rg * 8];
#pragma unroll
                    for (int j = 0; j < 8; ++j) v[j] += wh[k][j] * b2f(sv[j]);
                }
                short8 o;
#pragma unroll
                for (int j = 0; j < 8; ++j) o[j] = f2b(v[j]);
                *(short8*)&t1[q * 32 + rg * 8] = o;
            }
        }
        __syncthreads();
        {
            float ww[3][8];
#pragma unroll
            for (int k = 0; k < 3; ++k) {
                const float4* pp_ = (const float4*)&ukf[(3 + k) * 64 + rbase + rg * 8];
                float4 u0 = pp_[0], u1 = pp_[1];
                ww[k][0]=u0.x; ww[k][1]=u0.y; ww[k][2]=u0.z; ww[k][3]=u0.w;
                ww[k][4]=u1.x; ww[k][5]=u1.y; ww[k][6]=u1.z; ww[k][7]=u1.w;
            }
            for (int item = tid; item < 1152; item += NTH) {
                int q2 = item >> 2;
                int oh = q2 / 72;
                int src = q2 + oh * 36;
                float v[8] = {};
#pragma unroll
                for (int k = 0; k < 3; ++k) {
                    short8 sv = *(const short8*)&t1[(src + k * 18) * 32 + rg * 8];
#pragma unroll
                    for (int j = 0; j < 8; ++j) v[j] += ww[k][j] * b2f(sv[j]);
                }
                short8 o;
#pragma unroll
                for (int j = 0; j < 8; ++j) o[j] = f2b(v[j]);
                *(short8*)&t0[q2 * 32 + rg * 8] = o;
            }
        }
        __syncthreads();
        {
            float wd[3][8];
#pragma unroll
            for (int k = 0; k < 3; ++k) {
                const float4* pp_ = (const float4*)&ukf[(6 + k) * 64 + rbase + rg * 8];
                float4 u0 = pp_[0], u1 = pp_[1];
                wd[k][0]=u0.x; wd[k][1]=u0.y; wd[k][2]=u0.z; wd[k][3]=u0.w;
                wd[k][4]=u1.x; wd[k][5]=u1.y; wd[k][6]=u1.z; wd[k][7]=u1.w;
            }
            for (int item = tid; item < 1024; item += NTH) {
                int pq = item >> 2;
                int src = pq + (pq >> 4) * 2;
                float v[8] = {};
#pragma unroll
                for (int k = 0; k < 3; ++k) {
                    short8 sv = *(const short8*)&t0[(src + k) * 32 + rg * 8];
#pragma unroll
                    for (int j = 0; j < 8; ++j) v[j] += wd[k][j] * b2f(sv[j]);
                }
                short8 o;
#pragma unroll
                for (int j = 0; j < 8; ++j) o[j] = f2b(v[j]);
                *(short8*)&t1[pq * 32 + rg * 8] = o;
            }
        }
        __syncthreads();
        {
            short8 bfr[4];
#pragma unroll
            for (int nt = 0; nt < 4; ++nt)
                bfr[nt] = *(const short8*)&ucot[(nt * 16 + l15) * 64 + rbase + quad * 8];
#pragma unroll
            for (int i = 0; i < 8; ++i) {
                int mt = wv * 2 + (i >> 2), nt = i & 3;
                short8 afr = *(const short8*)&t1[(mt * 16 + l15) * 32 + quad * 8];
                acc[i] = __builtin_amdgcn_mfma_f32_16x16x32_bf16(afr, bfr[nt], acc[i], 0, 0, 0);
            }
        }
    }

#pragma unroll
    for (int i = 0; i < 8; ++i) {
        int mt = wv * 2 + (i >> 2), nt = i & 3;
        int co = nt * 16 + l15;
        int oh = mt >> 2, ow = mt & 3;
        float bs = bias[co];
        float4 o4;
        o4.x = acc[i][0] + bs; o4.y = acc[i][1] + bs;
        o4.z = acc[i][2] + bs; o4.w = acc[i][3] + bs;
        long addr = ((long)(b * 64 + co) << 18) + ((long)(h0 + oh) << 12)
                  + ((w0 + ow) << 6) + (d0 + quad * 4);
        *(float4*)&out[addr] = o4;
    }
}

extern "C" void kernel_launch(void* const* d_in, const int* in_sizes, int n_in,
                              void* d_out, int out_size, void* d_ws, size_t ws_size,
                              hipStream_t stream) {
    const float* x    = (const float*)d_in[0];
    const float* Ukh  = (const float*)d_in[1];
    const float* Ukw  = (const float*)d_in[2];
    const float* Ukd  = (const float*)d_in[3];
    const float* Ucin = (const float*)d_in[4];
    const float* Uco  = (const float*)d_in[5];
    const float* bias = (const float*)d_in[6];
    float* out = (float*)d_out;

    const size_t needT = (size_t)2 * 262144 * 64 * 2;   // 64 MiB for t (bf16)
    const size_t needM = (4096 + 2048) * 2;             // 12 KiB ucotT + ucinT
    if (ws_size >= needT) {
        short* t = (short*)d_ws;
        short* ucotT = nullptr;
        short* ucinT = nullptr;
        if (ws_size >= needT + needM) {
            ucotT = (short*)((char*)d_ws + needT);
            ucinT = ucotT + 4096;
            k0_prep<<<96, 64, 0, stream>>>(Uco, Ucin, ucotT, ucinT);
        }
        k1_channel<<<2048, 256, 0, stream>>>(x, Ucin, ucinT, t);
        k2_conv_gemm<<<8192, 256, 0, stream>>>(t, Ukh, Ukw, Ukd, Uco, bias, ucotT, out);
    } else {
        (void)hipFuncSetAttribute((const void*)cpd_conv3d_fused_fb,
                                  hipFuncAttributeMaxDynamicSharedMemorySize,
                                  SMEM_BYTES);
        cpd_conv3d_fused_fb<<<2048, NTH, SMEM_BYTES, stream>>>(
            x, Ukh, Ukw, Ukd, Ucin, Uco, bias, out);
    }
}